// Round 9
// baseline (677.787 us; speedup 1.0000x reference)
//
#include <hip/hip_runtime.h>
#include <hip/hip_bf16.h>
#include <math.h>

#define WSA(x) (((x) + 255) & ~(size_t)255)

// ---------------- zero init (re-poisoned ws each call) ----------------
__global__ void zero_kernel(int* __restrict__ deg, float* __restrict__ accum, int N) {
    int i = blockIdx.x * blockDim.x + threadIdx.x;
    if (i < N) deg[i] = 0;
    if (i < 260) accum[i] = 0.0f;
}

// ---------------- degree histogram ----------------
__global__ void deg_kernel(const int* __restrict__ dst, int E, int* __restrict__ deg) {
    for (int i = blockIdx.x * blockDim.x + threadIdx.x; i < E; i += gridDim.x * blockDim.x)
        atomicAdd(&deg[dst[i]], 1);
}

// ---------------- exclusive scan + dis/dis2 + cursor init (single block) ----------------
__global__ __launch_bounds__(1024) void scan_kernel(const int* __restrict__ deg, int N, int E,
                                                    int* __restrict__ rowstart, int* __restrict__ cursor,
                                                    float* __restrict__ dis, float* __restrict__ dis2) {
    __shared__ int part[1024];
    int t = threadIdx.x;
    int C = (N + 1023) / 1024;
    int lo = t * C, hi = min(lo + C, N);
    int s = 0;
    for (int i = lo; i < hi; i++) s += deg[i];
    part[t] = s;
    __syncthreads();
    for (int off = 1; off < 1024; off <<= 1) {
        int v = 0;
        if (t >= off) v = part[t - off];
        __syncthreads();
        if (t >= off) part[t] += v;
        __syncthreads();
    }
    int run = (t == 0) ? 0 : part[t - 1];
    for (int i = lo; i < hi; i++) {
        rowstart[i] = run;
        cursor[i] = run;
        int d = deg[i];
        run += d;
        float df = (float)d + 1.0f;
        dis[i]  = rsqrtf(df);
        dis2[i] = 1.0f / df;
    }
    if (t == 0) rowstart[N] = E;
}

// ---------------- CSR fill: pack {src, w=dis[src]*dis[dst]} ----------------
__global__ void fill_kernel(const int* __restrict__ src, const int* __restrict__ dst, int E,
                            int* __restrict__ cursor, const float* __restrict__ dis,
                            unsigned long long* __restrict__ csr) {
    for (int i = blockIdx.x * blockDim.x + threadIdx.x; i < E; i += gridDim.x * blockDim.x) {
        int s = src[i], d = dst[i];
        int pos = atomicAdd(&cursor[d], 1);
        float w = dis[s] * dis[d];
        unsigned long long pk = ((unsigned long long)__float_as_uint(w) << 32) | (unsigned int)s;
        csr[pos] = pk;
    }
}

// ---------------- layer 0: h0 = relu(concat(onehot, x02) @ W0 + b0) ----------------
__global__ __launch_bounds__(256) void h0_kernel(const float* __restrict__ x, const float* __restrict__ W0,
                                                 const float* __restrict__ b0, float* __restrict__ h0, int N) {
    __shared__ float w[60 * 64];
    __shared__ float bs[64];
    for (int i = threadIdx.x; i < 60 * 64; i += 256) w[i] = W0[i];
    if (threadIdx.x < 64) bs[threadIdx.x] = b0[threadIdx.x];
    __syncthreads();
    int lane = threadIdx.x & 63, wv = threadIdx.x >> 6;
    for (int n = blockIdx.x * 4 + wv; n < N; n += gridDim.x * 4) {
        const float* xr = x + (size_t)n * 41;
        int ct = (int)xr[0];
        float acc = w[ct * 64 + lane] + bs[lane];
        #pragma unroll
        for (int j = 0; j < 40; j++) acc += xr[1 + j] * w[(20 + j) * 64 + lane];
        h0[(size_t)n * 64 + lane] = fmaxf(acc, 0.0f);
    }
}

// ---------------- T = H @ W (H: N x 64, W: 64 x 64) ----------------
__global__ __launch_bounds__(256) void gemm64_kernel(const float* __restrict__ H, const float* __restrict__ W,
                                                     float* __restrict__ T, int N) {
    __shared__ float w[64 * 64];
    for (int i = threadIdx.x; i < 4096; i += 256) w[i] = W[i];
    __syncthreads();
    int lane = threadIdx.x & 63, wv = threadIdx.x >> 6;
    int gw = blockIdx.x * 4 + wv;
    for (int r0 = gw * 4; r0 < N; r0 += gridDim.x * 16) {
        float a0 = 0.f, a1 = 0.f, a2 = 0.f, a3 = 0.f;
        const float* hp = H + (size_t)r0 * 64;
        #pragma unroll
        for (int k = 0; k < 64; k++) {
            float wk = w[k * 64 + lane];
            a0 += hp[k] * wk;
            a1 += hp[64 + k] * wk;
            a2 += hp[128 + k] * wk;
            a3 += hp[192 + k] * wk;
        }
        float* tp = T + (size_t)r0 * 64 + lane;
        tp[0] = a0; tp[64] = a1; tp[128] = a2; tp[192] = a3;
    }
}

// ---------------- aggregation (float4, 4 nodes/wave):
// out[n] = sum_e w*T[src] + T[n]*dis2[n] + b (opt +identity, opt relu)
// 16-lane group g owns node n0+wv*4+g; lane c holds feats [4c..4c+3].
// Per edge-load instruction the wave moves 4 rows x 256B = 1KB (16B/lane).
#define AGG_RELU 1
#define AGG_IDENT 2
__global__ __launch_bounds__(256) void agg_kernel(const float* __restrict__ T, const unsigned long long* __restrict__ csr,
                                                  const int* __restrict__ rowstart, const float* __restrict__ dis2,
                                                  const float* __restrict__ b, const float* __restrict__ identity,
                                                  float* __restrict__ out, int N, int flags) {
    int c  = threadIdx.x & 15;         // feat-quad index within node
    int g  = (threadIdx.x >> 4) & 3;   // group within wave
    int wv = threadIdx.x >> 6;         // wave within block
    float4 bv = *(const float4*)(b + 4 * c);
    for (int n0 = blockIdx.x * 16; n0 < N; n0 += gridDim.x * 16) {
        int n = n0 + wv * 4 + g;
        if (n < N) {
            float4 acc = *(const float4*)(T + (size_t)n * 64 + 4 * c);
            float d2 = dis2[n];
            acc.x = acc.x * d2 + bv.x;
            acc.y = acc.y * d2 + bv.y;
            acc.z = acc.z * d2 + bv.z;
            acc.w = acc.w * d2 + bv.w;
            int e0 = rowstart[n], e1 = rowstart[n + 1];
            for (int e = e0; e < e1; e++) {
                unsigned long long pk = csr[e];
                int s   = (int)(unsigned int)(pk & 0xFFFFFFFFull);
                float w = __uint_as_float((unsigned int)(pk >> 32));
                float4 v = *(const float4*)(T + (size_t)s * 64 + 4 * c);
                acc.x += w * v.x;
                acc.y += w * v.y;
                acc.z += w * v.z;
                acc.w += w * v.w;
            }
            if (flags & AGG_IDENT) {
                float4 iv = *(const float4*)(identity + (size_t)n * 64 + 4 * c);
                acc.x += iv.x; acc.y += iv.y; acc.z += iv.z; acc.w += iv.w;
            }
            if (flags & AGG_RELU) {
                acc.x = fmaxf(acc.x, 0.0f);
                acc.y = fmaxf(acc.y, 0.0f);
                acc.z = fmaxf(acc.z, 0.0f);
                acc.w = fmaxf(acc.w, 0.0f);
            }
            *(float4*)(out + (size_t)n * 64 + 4 * c) = acc;
        }
    }
}

// ---------------- s = softmax(out @ Wl + bl); den += deg[n]*sum(s^2) ----------------
__global__ __launch_bounds__(256) void slogits_kernel(const float* __restrict__ out, const float* __restrict__ Wl,
                                                      const float* __restrict__ bl, const int* __restrict__ deg,
                                                      float* __restrict__ s, float* __restrict__ accum, int N) {
    __shared__ float w[64 * 16];
    __shared__ float bs[16];
    __shared__ float red[16];
    for (int i = threadIdx.x; i < 1024; i += 256) w[i] = Wl[i];
    if (threadIdx.x < 16) bs[threadIdx.x] = bl[threadIdx.x];
    __syncthreads();
    int k = threadIdx.x & 15, grp = threadIdx.x >> 4;   // 16 groups of 16 lanes
    float denpart = 0.0f;
    for (int n = blockIdx.x * 16 + grp; n < N; n += gridDim.x * 16) {
        const float* orow = out + (size_t)n * 64;
        float acc = bs[k];
        #pragma unroll
        for (int j = 0; j < 64; j++) acc += orow[j] * w[j * 16 + k];
        float m = acc;
        for (int off = 8; off; off >>= 1) m = fmaxf(m, __shfl_xor(m, off, 16));
        float e = __expf(acc - m);
        float sum = e;
        for (int off = 8; off; off >>= 1) sum += __shfl_xor(sum, off, 16);
        float sv = e / sum;
        s[(size_t)n * 16 + k] = sv;
        float ssum = sv * sv;
        for (int off = 8; off; off >>= 1) ssum += __shfl_xor(ssum, off, 16);
        if (k == 0) denpart += (float)deg[n] * ssum;
    }
    if (k == 0) red[grp] = denpart;
    __syncthreads();
    if (threadIdx.x == 0) {
        float tot = 0.f;
        for (int i = 0; i < 16; i++) tot += red[i];
        atomicAdd(&accum[1], tot);
    }
}

// ---------------- ss = s^T @ s (16x16), accumulated ----------------
__global__ __launch_bounds__(256) void sst_kernel(const float* __restrict__ s, int N, float* __restrict__ accum) {
    __shared__ float tile[256 * 16];
    int a = threadIdx.x >> 4, b = threadIdx.x & 15;
    float acc = 0.0f;
    for (int base = blockIdx.x * 256; base < N; base += gridDim.x * 256) {
        int cnt = min(256, N - base);
        for (int i = threadIdx.x; i < cnt * 16; i += 256) tile[i] = s[(size_t)base * 16 + i];
        __syncthreads();
        for (int i = 0; i < cnt; i++) acc += tile[i * 16 + a] * tile[i * 16 + b];
        __syncthreads();
    }
    atomicAdd(&accum[2 + threadIdx.x], acc);
}

// ---------------- num = sum_e sum_k s[src][k]*s[dst][k] ----------------
__global__ __launch_bounds__(256) void num_kernel(const int* __restrict__ src, const int* __restrict__ dst,
                                                  const float* __restrict__ s, int E, float* __restrict__ accum) {
    int k = threadIdx.x & 15, grp = threadIdx.x >> 4;
    float acc = 0.0f;
    for (int e = blockIdx.x * 16 + grp; e < E; e += gridDim.x * 16) {
        int a = src[e], b = dst[e];
        acc += s[(size_t)a * 16 + k] * s[(size_t)b * 16 + k];
    }
    __shared__ float red[256];
    red[threadIdx.x] = acc;
    __syncthreads();
    for (int off = 128; off; off >>= 1) {
        if (threadIdx.x < off) red[threadIdx.x] += red[threadIdx.x + off];
        __syncthreads();
    }
    if (threadIdx.x == 0) atomicAdd(&accum[0], red[0]);
}

// ---------------- final: mc = -(num/den); o = ||ss/||ss|| - I/4||_F ----------------
__global__ __launch_bounds__(256) void final_kernel(const float* __restrict__ accum, float* __restrict__ out) {
    __shared__ float red[256];
    __shared__ float nrm_s;
    int t = threadIdx.x;
    float v = accum[2 + t];
    red[t] = v * v;
    __syncthreads();
    for (int off = 128; off; off >>= 1) {
        if (t < off) red[t] += red[t + off];
        __syncthreads();
    }
    if (t == 0) nrm_s = sqrtf(red[0]);
    __syncthreads();
    float d = v / nrm_s - (((t % 17) == 0) ? 0.25f : 0.0f);
    red[t] = d * d;
    __syncthreads();
    for (int off = 128; off; off >>= 1) {
        if (t < off) red[t] += red[t + off];
        __syncthreads();
    }
    if (t == 0) {
        out[0] = -(accum[0] / accum[1]);
        out[1] = sqrtf(red[0]);
    }
}

extern "C" void kernel_launch(void* const* d_in, const int* in_sizes, int n_in,
                              void* d_out, int out_size, void* d_ws, size_t ws_size,
                              hipStream_t stream) {
    const float* x  = (const float*)d_in[0];
    const int*   ei = (const int*)d_in[1];
    const float* W0 = (const float*)d_in[4];
    const float* b0 = (const float*)d_in[5];
    const float* W1 = (const float*)d_in[6];
    const float* b1 = (const float*)d_in[7];
    const float* W2 = (const float*)d_in[8];
    const float* b2 = (const float*)d_in[9];
    const float* W3 = (const float*)d_in[10];
    const float* b3 = (const float*)d_in[11];
    const float* Wl = (const float*)d_in[12];
    const float* bl = (const float*)d_in[13];
    float* outp = (float*)d_out;

    int N = in_sizes[0] / 41;   // x: (N, 1+2G) = (N, 41)
    int E = in_sizes[1] / 2;    // edge_index: (2, E)
    const int* src = ei;
    const int* dst = ei + E;

    // workspace layout
    char* p = (char*)d_ws;
    float* accum   = (float*)p;                 p += WSA(260 * 4);          // [0]=num [1]=den [2..257]=ss
    int*   deg     = (int*)p;                   p += WSA((size_t)N * 4);
    int*   rowstart= (int*)p;                   p += WSA((size_t)(N + 1) * 4);
    int*   cursor  = (int*)p;                   p += WSA((size_t)N * 4);
    float* dis     = (float*)p;                 p += WSA((size_t)N * 4);
    float* dis2    = (float*)p;                 p += WSA((size_t)N * 4);
    unsigned long long* csr = (unsigned long long*)p; p += WSA((size_t)E * 8);
    float* ident   = (float*)p;                 p += WSA((size_t)N * 64 * 4);
    float* bufA    = (float*)p;                 p += WSA((size_t)N * 64 * 4);
    float* bufB    = (float*)p;                 p += WSA((size_t)N * 64 * 4);
    float* sbuf    = (float*)p;                 p += WSA((size_t)N * 16 * 4);

    int nwaveblk = (N + 3) / 4;        // one node per wave, 4 waves/block (h0)
    int aggblk   = (N + 15) / 16;      // 16 nodes per block (agg: 4 nodes/wave)
    int gemmblk  = (N + 15) / 16;      // 16 rows per block
    int grpblk   = (N + 15) / 16;      // 16 nodes per block (16-lane groups)
    int tileblk  = (N + 255) / 256;

    zero_kernel<<<(N + 255) / 256, 256, 0, stream>>>(deg, accum, N);
    deg_kernel<<<2048, 256, 0, stream>>>(dst, E, deg);
    scan_kernel<<<1, 1024, 0, stream>>>(deg, N, E, rowstart, cursor, dis, dis2);
    fill_kernel<<<2048, 256, 0, stream>>>(src, dst, E, cursor, dis, csr);

    // layer 0 (h0 = identity)
    h0_kernel<<<nwaveblk, 256, 0, stream>>>(x, W0, b0, ident, N);

    // layer 1: T = ident @ W1 -> bufA ; agg -> bufB (relu)
    gemm64_kernel<<<gemmblk, 256, 0, stream>>>(ident, W1, bufA, N);
    agg_kernel<<<aggblk, 256, 0, stream>>>(bufA, csr, rowstart, dis2, b1, ident, bufB, N, AGG_RELU);

    // layer 2: T = bufB @ W2 -> bufA ; agg -> bufB (relu)
    gemm64_kernel<<<gemmblk, 256, 0, stream>>>(bufB, W2, bufA, N);
    agg_kernel<<<aggblk, 256, 0, stream>>>(bufA, csr, rowstart, dis2, b2, ident, bufB, N, AGG_RELU);

    // layer 3: T = bufB @ W3 -> bufA ; agg + identity -> bufB (relu)
    gemm64_kernel<<<gemmblk, 256, 0, stream>>>(bufB, W3, bufA, N);
    agg_kernel<<<aggblk, 256, 0, stream>>>(bufA, csr, rowstart, dis2, b3, ident, bufB, N, AGG_RELU | AGG_IDENT);

    // losses
    slogits_kernel<<<grpblk, 256, 0, stream>>>(bufB, Wl, bl, deg, sbuf, accum, N);
    sst_kernel<<<tileblk, 256, 0, stream>>>(sbuf, N, accum);
    num_kernel<<<2048, 256, 0, stream>>>(src, dst, sbuf, E, accum);
    final_kernel<<<1, 256, 0, stream>>>(accum, outp);
}

// Round 12
// 527.464 us; speedup vs baseline: 1.2850x; 1.2850x over previous
//
#include <hip/hip_runtime.h>
#include <hip/hip_bf16.h>
#include <math.h>

#define WSA(x) (((x) + 255) & ~(size_t)255)

// ---------------- zero init (re-poisoned ws each call) ----------------
__global__ void zero_kernel(int* __restrict__ deg, float* __restrict__ accum, int N) {
    int i = blockIdx.x * blockDim.x + threadIdx.x;
    if (i < N) deg[i] = 0;
    if (i < 260) accum[i] = 0.0f;
}

// ---------------- degree histogram ----------------
__global__ void deg_kernel(const int* __restrict__ dst, int E, int* __restrict__ deg) {
    for (int i = blockIdx.x * blockDim.x + threadIdx.x; i < E; i += gridDim.x * blockDim.x)
        atomicAdd(&deg[dst[i]], 1);
}

// ---------------- hierarchical scan, stage 1: per-block sums of deg ----------------
__global__ __launch_bounds__(256) void partial_kernel(const int* __restrict__ deg, int N,
                                                      int* __restrict__ blocksum) {
    __shared__ int sh[256];
    int t = threadIdx.x;
    int i = blockIdx.x * 256 + t;
    sh[t] = (i < N) ? deg[i] : 0;
    __syncthreads();
    for (int off = 128; off; off >>= 1) {
        if (t < off) sh[t] += sh[t + off];
        __syncthreads();
    }
    if (t == 0) blocksum[blockIdx.x] = sh[0];
}

// ---------------- stage 2: exclusive scan of block sums (single block) ----------------
__global__ __launch_bounds__(1024) void scanblocks_kernel(const int* __restrict__ blocksum,
                                                          int nsb, int* __restrict__ blockoff) {
    __shared__ int part[1024];
    int t = threadIdx.x;
    part[t] = (t < nsb) ? blocksum[t] : 0;
    __syncthreads();
    for (int off = 1; off < 1024; off <<= 1) {
        int v = 0;
        if (t >= off) v = part[t - off];
        __syncthreads();
        if (t >= off) part[t] += v;
        __syncthreads();
    }
    if (t < nsb) blockoff[t] = (t == 0) ? 0 : part[t - 1];
}

// ---------------- stage 3: in-block scan + rowstart/cursor/dis/dis2 fill ----------------
__global__ __launch_bounds__(256) void fillrow_kernel(const int* __restrict__ deg, const int* __restrict__ blockoff,
                                                      int N, int E, int* __restrict__ rowstart,
                                                      int* __restrict__ cursor, float* __restrict__ dis,
                                                      float* __restrict__ dis2) {
    __shared__ int sh[256];
    int t = threadIdx.x;
    int i = blockIdx.x * 256 + t;
    int d = (i < N) ? deg[i] : 0;
    sh[t] = d;
    __syncthreads();
    for (int off = 1; off < 256; off <<= 1) {
        int v = 0;
        if (t >= off) v = sh[t - off];
        __syncthreads();
        if (t >= off) sh[t] += v;
        __syncthreads();
    }
    if (i < N) {
        int run = blockoff[blockIdx.x] + ((t == 0) ? 0 : sh[t - 1]);
        rowstart[i] = run;
        cursor[i] = run;
        float df = (float)d + 1.0f;
        dis[i]  = rsqrtf(df);
        dis2[i] = 1.0f / df;
    }
    if (i == 0) rowstart[N] = E;
}

// ---------------- CSR fill: pack {src, w=dis[src]*dis[dst]} ----------------
__global__ void fill_kernel(const int* __restrict__ src, const int* __restrict__ dst, int E,
                            int* __restrict__ cursor, const float* __restrict__ dis,
                            unsigned long long* __restrict__ csr) {
    for (int i = blockIdx.x * blockDim.x + threadIdx.x; i < E; i += gridDim.x * blockDim.x) {
        int s = src[i], d = dst[i];
        int pos = atomicAdd(&cursor[d], 1);
        float w = dis[s] * dis[d];
        unsigned long long pk = ((unsigned long long)__float_as_uint(w) << 32) | (unsigned int)s;
        csr[pos] = pk;
    }
}

// ---------------- layer 0: h0 = relu(concat(onehot, x02) @ W0 + b0) ----------------
__global__ __launch_bounds__(256) void h0_kernel(const float* __restrict__ x, const float* __restrict__ W0,
                                                 const float* __restrict__ b0, float* __restrict__ h0, int N) {
    __shared__ float w[60 * 64];
    __shared__ float bs[64];
    for (int i = threadIdx.x; i < 60 * 64; i += 256) w[i] = W0[i];
    if (threadIdx.x < 64) bs[threadIdx.x] = b0[threadIdx.x];
    __syncthreads();
    int lane = threadIdx.x & 63, wv = threadIdx.x >> 6;
    for (int n = blockIdx.x * 4 + wv; n < N; n += gridDim.x * 4) {
        const float* xr = x + (size_t)n * 41;
        int ct = (int)xr[0];
        float acc = w[ct * 64 + lane] + bs[lane];
        #pragma unroll
        for (int j = 0; j < 40; j++) acc += xr[1 + j] * w[(20 + j) * 64 + lane];
        h0[(size_t)n * 64 + lane] = fmaxf(acc, 0.0f);
    }
}

// ---------------- T = H @ W (H: N x 64, W: 64 x 64) ----------------
__global__ __launch_bounds__(256) void gemm64_kernel(const float* __restrict__ H, const float* __restrict__ W,
                                                     float* __restrict__ T, int N) {
    __shared__ float w[64 * 64];
    for (int i = threadIdx.x; i < 4096; i += 256) w[i] = W[i];
    __syncthreads();
    int lane = threadIdx.x & 63, wv = threadIdx.x >> 6;
    int gw = blockIdx.x * 4 + wv;
    for (int r0 = gw * 4; r0 < N; r0 += gridDim.x * 16) {
        float a0 = 0.f, a1 = 0.f, a2 = 0.f, a3 = 0.f;
        const float* hp = H + (size_t)r0 * 64;
        #pragma unroll
        for (int k = 0; k < 64; k++) {
            float wk = w[k * 64 + lane];
            a0 += hp[k] * wk;
            a1 += hp[64 + k] * wk;
            a2 += hp[128 + k] * wk;
            a3 += hp[192 + k] * wk;
        }
        float* tp = T + (size_t)r0 * 64 + lane;
        tp[0] = a0; tp[64] = a1; tp[128] = a2; tp[192] = a3;
    }
}

// ---------------- aggregation (float4, 4 nodes/wave):
// out[n] = sum_e w*T[src] + T[n]*dis2[n] + b (opt +identity, opt relu)
#define AGG_RELU 1
#define AGG_IDENT 2
__global__ __launch_bounds__(256) void agg_kernel(const float* __restrict__ T, const unsigned long long* __restrict__ csr,
                                                  const int* __restrict__ rowstart, const float* __restrict__ dis2,
                                                  const float* __restrict__ b, const float* __restrict__ identity,
                                                  float* __restrict__ out, int N, int flags) {
    int c  = threadIdx.x & 15;         // feat-quad index within node
    int g  = (threadIdx.x >> 4) & 3;   // group within wave
    int wv = threadIdx.x >> 6;         // wave within block
    float4 bv = *(const float4*)(b + 4 * c);
    for (int n0 = blockIdx.x * 16; n0 < N; n0 += gridDim.x * 16) {
        int n = n0 + wv * 4 + g;
        if (n < N) {
            float4 acc = *(const float4*)(T + (size_t)n * 64 + 4 * c);
            float d2 = dis2[n];
            acc.x = acc.x * d2 + bv.x;
            acc.y = acc.y * d2 + bv.y;
            acc.z = acc.z * d2 + bv.z;
            acc.w = acc.w * d2 + bv.w;
            int e0 = rowstart[n], e1 = rowstart[n + 1];
            for (int e = e0; e < e1; e++) {
                unsigned long long pk = csr[e];
                int s   = (int)(unsigned int)(pk & 0xFFFFFFFFull);
                float w = __uint_as_float((unsigned int)(pk >> 32));
                float4 v = *(const float4*)(T + (size_t)s * 64 + 4 * c);
                acc.x += w * v.x;
                acc.y += w * v.y;
                acc.z += w * v.z;
                acc.w += w * v.w;
            }
            if (flags & AGG_IDENT) {
                float4 iv = *(const float4*)(identity + (size_t)n * 64 + 4 * c);
                acc.x += iv.x; acc.y += iv.y; acc.z += iv.z; acc.w += iv.w;
            }
            if (flags & AGG_RELU) {
                acc.x = fmaxf(acc.x, 0.0f);
                acc.y = fmaxf(acc.y, 0.0f);
                acc.z = fmaxf(acc.z, 0.0f);
                acc.w = fmaxf(acc.w, 0.0f);
            }
            *(float4*)(out + (size_t)n * 64 + 4 * c) = acc;
        }
    }
}

// ---------------- s = softmax(out @ Wl + bl); den += deg[n]*sum(s^2) ----------------
__global__ __launch_bounds__(256) void slogits_kernel(const float* __restrict__ out, const float* __restrict__ Wl,
                                                      const float* __restrict__ bl, const int* __restrict__ deg,
                                                      float* __restrict__ s, float* __restrict__ accum, int N) {
    __shared__ float w[64 * 16];
    __shared__ float bs[16];
    __shared__ float red[16];
    for (int i = threadIdx.x; i < 1024; i += 256) w[i] = Wl[i];
    if (threadIdx.x < 16) bs[threadIdx.x] = bl[threadIdx.x];
    __syncthreads();
    int k = threadIdx.x & 15, grp = threadIdx.x >> 4;   // 16 groups of 16 lanes
    float denpart = 0.0f;
    for (int n = blockIdx.x * 16 + grp; n < N; n += gridDim.x * 16) {
        const float* orow = out + (size_t)n * 64;
        float acc = bs[k];
        #pragma unroll
        for (int j = 0; j < 64; j++) acc += orow[j] * w[j * 16 + k];
        float m = acc;
        for (int off = 8; off; off >>= 1) m = fmaxf(m, __shfl_xor(m, off, 16));
        float e = __expf(acc - m);
        float sum = e;
        for (int off = 8; off; off >>= 1) sum += __shfl_xor(sum, off, 16);
        float sv = e / sum;
        s[(size_t)n * 16 + k] = sv;
        float ssum = sv * sv;
        for (int off = 8; off; off >>= 1) ssum += __shfl_xor(ssum, off, 16);
        if (k == 0) denpart += (float)deg[n] * ssum;
    }
    if (k == 0) red[grp] = denpart;
    __syncthreads();
    if (threadIdx.x == 0) {
        float tot = 0.f;
        for (int i = 0; i < 16; i++) tot += red[i];
        atomicAdd(&accum[1], tot);
    }
}

// ---------------- ss = s^T @ s (16x16), accumulated ----------------
__global__ __launch_bounds__(256) void sst_kernel(const float* __restrict__ s, int N, float* __restrict__ accum) {
    __shared__ float tile[256 * 16];
    int a = threadIdx.x >> 4, b = threadIdx.x & 15;
    float acc = 0.0f;
    for (int base = blockIdx.x * 256; base < N; base += gridDim.x * 256) {
        int cnt = min(256, N - base);
        for (int i = threadIdx.x; i < cnt * 16; i += 256) tile[i] = s[(size_t)base * 16 + i];
        __syncthreads();
        for (int i = 0; i < cnt; i++) acc += tile[i * 16 + a] * tile[i * 16 + b];
        __syncthreads();
    }
    atomicAdd(&accum[2 + threadIdx.x], acc);
}

// ---------------- num = sum_e sum_k s[src][k]*s[dst][k] ----------------
__global__ __launch_bounds__(256) void num_kernel(const int* __restrict__ src, const int* __restrict__ dst,
                                                  const float* __restrict__ s, int E, float* __restrict__ accum) {
    int k = threadIdx.x & 15, grp = threadIdx.x >> 4;
    float acc = 0.0f;
    for (int e = blockIdx.x * 16 + grp; e < E; e += gridDim.x * 16) {
        int a = src[e], b = dst[e];
        acc += s[(size_t)a * 16 + k] * s[(size_t)b * 16 + k];
    }
    __shared__ float red[256];
    red[threadIdx.x] = acc;
    __syncthreads();
    for (int off = 128; off; off >>= 1) {
        if (threadIdx.x < off) red[threadIdx.x] += red[threadIdx.x + off];
        __syncthreads();
    }
    if (threadIdx.x == 0) atomicAdd(&accum[0], red[0]);
}

// ---------------- final: mc = -(num/den); o = ||ss/||ss|| - I/4||_F ----------------
__global__ __launch_bounds__(256) void final_kernel(const float* __restrict__ accum, float* __restrict__ out) {
    __shared__ float red[256];
    __shared__ float nrm_s;
    int t = threadIdx.x;
    float v = accum[2 + t];
    red[t] = v * v;
    __syncthreads();
    for (int off = 128; off; off >>= 1) {
        if (t < off) red[t] += red[t + off];
        __syncthreads();
    }
    if (t == 0) nrm_s = sqrtf(red[0]);
    __syncthreads();
    float d = v / nrm_s - (((t % 17) == 0) ? 0.25f : 0.0f);
    red[t] = d * d;
    __syncthreads();
    for (int off = 128; off; off >>= 1) {
        if (t < off) red[t] += red[t + off];
        __syncthreads();
    }
    if (t == 0) {
        out[0] = -(accum[0] / accum[1]);
        out[1] = sqrtf(red[0]);
    }
}

extern "C" void kernel_launch(void* const* d_in, const int* in_sizes, int n_in,
                              void* d_out, int out_size, void* d_ws, size_t ws_size,
                              hipStream_t stream) {
    const float* x  = (const float*)d_in[0];
    const int*   ei = (const int*)d_in[1];
    const float* W0 = (const float*)d_in[4];
    const float* b0 = (const float*)d_in[5];
    const float* W1 = (const float*)d_in[6];
    const float* b1 = (const float*)d_in[7];
    const float* W2 = (const float*)d_in[8];
    const float* b2 = (const float*)d_in[9];
    const float* W3 = (const float*)d_in[10];
    const float* b3 = (const float*)d_in[11];
    const float* Wl = (const float*)d_in[12];
    const float* bl = (const float*)d_in[13];
    float* outp = (float*)d_out;

    int N = in_sizes[0] / 41;   // x: (N, 1+2G) = (N, 41)
    int E = in_sizes[1] / 2;    // edge_index: (2, E)
    const int* src = ei;
    const int* dst = ei + E;

    int nsb = (N + 255) / 256;         // scan blocks (196 for N=50k)

    // workspace layout
    char* p = (char*)d_ws;
    float* accum   = (float*)p;                 p += WSA(260 * 4);          // [0]=num [1]=den [2..257]=ss
    int*   deg     = (int*)p;                   p += WSA((size_t)N * 4);
    int*   rowstart= (int*)p;                   p += WSA((size_t)(N + 1) * 4);
    int*   cursor  = (int*)p;                   p += WSA((size_t)N * 4);
    float* dis     = (float*)p;                 p += WSA((size_t)N * 4);
    float* dis2    = (float*)p;                 p += WSA((size_t)N * 4);
    int*   blocksum= (int*)p;                   p += WSA((size_t)nsb * 4);
    int*   blockoff= (int*)p;                   p += WSA((size_t)nsb * 4);
    unsigned long long* csr = (unsigned long long*)p; p += WSA((size_t)E * 8);
    float* ident   = (float*)p;                 p += WSA((size_t)N * 64 * 4);
    float* bufA    = (float*)p;                 p += WSA((size_t)N * 64 * 4);
    float* bufB    = (float*)p;                 p += WSA((size_t)N * 64 * 4);
    float* sbuf    = (float*)p;                 p += WSA((size_t)N * 16 * 4);

    int nwaveblk = (N + 3) / 4;        // one node per wave, 4 waves/block (h0)
    int aggblk   = (N + 15) / 16;      // 16 nodes per block (agg: 4 nodes/wave)
    int gemmblk  = (N + 15) / 16;      // 16 rows per block
    int grpblk   = (N + 15) / 16;      // 16 nodes per block (16-lane groups)
    int tileblk  = (N + 255) / 256;

    zero_kernel<<<(N + 255) / 256, 256, 0, stream>>>(deg, accum, N);
    deg_kernel<<<2048, 256, 0, stream>>>(dst, E, deg);
    // hierarchical scan (replaces single-block scan_kernel: was 161us on 1 CU)
    partial_kernel<<<nsb, 256, 0, stream>>>(deg, N, blocksum);
    scanblocks_kernel<<<1, 1024, 0, stream>>>(blocksum, nsb, blockoff);
    fillrow_kernel<<<nsb, 256, 0, stream>>>(deg, blockoff, N, E, rowstart, cursor, dis, dis2);
    fill_kernel<<<2048, 256, 0, stream>>>(src, dst, E, cursor, dis, csr);

    // layer 0 (h0 = identity)
    h0_kernel<<<nwaveblk, 256, 0, stream>>>(x, W0, b0, ident, N);

    // layer 1: T = ident @ W1 -> bufA ; agg -> bufB (relu)
    gemm64_kernel<<<gemmblk, 256, 0, stream>>>(ident, W1, bufA, N);
    agg_kernel<<<aggblk, 256, 0, stream>>>(bufA, csr, rowstart, dis2, b1, ident, bufB, N, AGG_RELU);

    // layer 2: T = bufB @ W2 -> bufA ; agg -> bufB (relu)
    gemm64_kernel<<<gemmblk, 256, 0, stream>>>(bufB, W2, bufA, N);
    agg_kernel<<<aggblk, 256, 0, stream>>>(bufA, csr, rowstart, dis2, b2, ident, bufB, N, AGG_RELU);

    // layer 3: T = bufB @ W3 -> bufA ; agg + identity -> bufB (relu)
    gemm64_kernel<<<gemmblk, 256, 0, stream>>>(bufB, W3, bufA, N);
    agg_kernel<<<aggblk, 256, 0, stream>>>(bufA, csr, rowstart, dis2, b3, ident, bufB, N, AGG_RELU | AGG_IDENT);

    // losses
    slogits_kernel<<<grpblk, 256, 0, stream>>>(bufB, Wl, bl, deg, sbuf, accum, N);
    sst_kernel<<<tileblk, 256, 0, stream>>>(sbuf, N, accum);
    num_kernel<<<2048, 256, 0, stream>>>(src, dst, sbuf, E, accum);
    final_kernel<<<1, 256, 0, stream>>>(accum, outp);
}

// Round 13
// 467.245 us; speedup vs baseline: 1.4506x; 1.1289x over previous
//
#include <hip/hip_runtime.h>
#include <hip/hip_bf16.h>
#include <math.h>

#define WSA(x) (((x) + 255) & ~(size_t)255)

// ---------------- zero init (re-poisoned ws each call) ----------------
__global__ void zero_kernel(int* __restrict__ deg, float* __restrict__ accum, int N) {
    int i = blockIdx.x * blockDim.x + threadIdx.x;
    if (i < N) deg[i] = 0;
    if (i < 260) accum[i] = 0.0f;
}

// ---------------- degree histogram ----------------
__global__ void deg_kernel(const int* __restrict__ dst, int E, int* __restrict__ deg) {
    for (int i = blockIdx.x * blockDim.x + threadIdx.x; i < E; i += gridDim.x * blockDim.x)
        atomicAdd(&deg[dst[i]], 1);
}

// ---------------- hierarchical scan, stage 1: per-block sums of deg ----------------
__global__ __launch_bounds__(256) void partial_kernel(const int* __restrict__ deg, int N,
                                                      int* __restrict__ blocksum) {
    __shared__ int sh[256];
    int t = threadIdx.x;
    int i = blockIdx.x * 256 + t;
    sh[t] = (i < N) ? deg[i] : 0;
    __syncthreads();
    for (int off = 128; off; off >>= 1) {
        if (t < off) sh[t] += sh[t + off];
        __syncthreads();
    }
    if (t == 0) blocksum[blockIdx.x] = sh[0];
}

// ---------------- stage 2: exclusive scan of block sums (single block) ----------------
__global__ __launch_bounds__(1024) void scanblocks_kernel(const int* __restrict__ blocksum,
                                                          int nsb, int* __restrict__ blockoff) {
    __shared__ int part[1024];
    int t = threadIdx.x;
    part[t] = (t < nsb) ? blocksum[t] : 0;
    __syncthreads();
    for (int off = 1; off < 1024; off <<= 1) {
        int v = 0;
        if (t >= off) v = part[t - off];
        __syncthreads();
        if (t >= off) part[t] += v;
        __syncthreads();
    }
    if (t < nsb) blockoff[t] = (t == 0) ? 0 : part[t - 1];
}

// ---------------- stage 3: in-block scan + rowstart/cursor/dis/dis2 fill ----------------
__global__ __launch_bounds__(256) void fillrow_kernel(const int* __restrict__ deg, const int* __restrict__ blockoff,
                                                      int N, int E, int* __restrict__ rowstart,
                                                      int* __restrict__ cursor, float* __restrict__ dis,
                                                      float* __restrict__ dis2) {
    __shared__ int sh[256];
    int t = threadIdx.x;
    int i = blockIdx.x * 256 + t;
    int d = (i < N) ? deg[i] : 0;
    sh[t] = d;
    __syncthreads();
    for (int off = 1; off < 256; off <<= 1) {
        int v = 0;
        if (t >= off) v = sh[t - off];
        __syncthreads();
        if (t >= off) sh[t] += v;
        __syncthreads();
    }
    if (i < N) {
        int run = blockoff[blockIdx.x] + ((t == 0) ? 0 : sh[t - 1]);
        rowstart[i] = run;
        cursor[i] = run;
        float df = (float)d + 1.0f;
        dis[i]  = rsqrtf(df);
        dis2[i] = 1.0f / df;
    }
    if (i == 0) rowstart[N] = E;
}

// ---------------- CSR fill: pack {src, w=dis[src]*dis[dst]} ----------------
__global__ void fill_kernel(const int* __restrict__ src, const int* __restrict__ dst, int E,
                            int* __restrict__ cursor, const float* __restrict__ dis,
                            unsigned long long* __restrict__ csr) {
    for (int i = blockIdx.x * blockDim.x + threadIdx.x; i < E; i += gridDim.x * blockDim.x) {
        int s = src[i], d = dst[i];
        int pos = atomicAdd(&cursor[d], 1);
        float w = dis[s] * dis[d];
        unsigned long long pk = ((unsigned long long)__float_as_uint(w) << 32) | (unsigned int)s;
        csr[pos] = pk;
    }
}

// ---------------- layer 0: h0 = relu(concat(onehot, x02) @ W0 + b0)
// x rows staged in LDS via coalesced loads (was: 41 broadcast scalar loads/wave)
__global__ __launch_bounds__(256) void h0_kernel(const float* __restrict__ x, const float* __restrict__ W0,
                                                 const float* __restrict__ b0, float* __restrict__ h0, int N) {
    __shared__ float w[60 * 64];
    __shared__ float bs[64];
    __shared__ float xs[4 * 41];
    for (int i = threadIdx.x; i < 60 * 64; i += 256) w[i] = W0[i];
    if (threadIdx.x < 64) bs[threadIdx.x] = b0[threadIdx.x];
    int n0 = blockIdx.x * 4;
    {
        int base = n0 * 41;
        int avail = N * 41 - base;
        int cnt = (avail < 4 * 41) ? avail : (4 * 41);
        if ((int)threadIdx.x < cnt) xs[threadIdx.x] = x[(size_t)base + threadIdx.x];
    }
    __syncthreads();
    int lane = threadIdx.x & 63, wv = threadIdx.x >> 6;
    int n = n0 + wv;
    if (n < N) {
        const float* xr = xs + wv * 41;
        int ct = (int)xr[0];
        float acc = w[ct * 64 + lane] + bs[lane];
        #pragma unroll
        for (int j = 0; j < 40; j++) acc += xr[1 + j] * w[(20 + j) * 64 + lane];
        h0[(size_t)n * 64 + lane] = fmaxf(acc, 0.0f);
    }
}

// ---------------- T = H @ W (H: N x 64, W: 64 x 64)
// H rows staged in LDS via coalesced float4 (was: 256 broadcast scalar loads/wave)
__global__ __launch_bounds__(256) void gemm64_kernel(const float* __restrict__ H, const float* __restrict__ W,
                                                     float* __restrict__ T, int N) {
    __shared__ float w[64 * 64];
    __shared__ float tile[16][68];   // pad 68: rows land on distinct banks
    for (int i = threadIdx.x; i < 4096; i += 256) w[i] = W[i];
    int n0 = blockIdx.x * 16;
    {
        int row = threadIdx.x >> 4, e4 = threadIdx.x & 15;
        int n = n0 + row;
        float4 v = make_float4(0.f, 0.f, 0.f, 0.f);
        if (n < N) v = *(const float4*)(H + (size_t)n * 64 + e4 * 4);
        *(float4*)&tile[row][e4 * 4] = v;
    }
    __syncthreads();
    int lane = threadIdx.x & 63, wv = threadIdx.x >> 6;
    int r0 = wv * 4;
    float a0 = 0.f, a1 = 0.f, a2 = 0.f, a3 = 0.f;
    #pragma unroll
    for (int k = 0; k < 64; k++) {
        float wk = w[k * 64 + lane];
        a0 += tile[r0 + 0][k] * wk;
        a1 += tile[r0 + 1][k] * wk;
        a2 += tile[r0 + 2][k] * wk;
        a3 += tile[r0 + 3][k] * wk;
    }
    int n = n0 + r0;
    if (n + 3 < N) {
        float* tp = T + (size_t)n * 64 + lane;
        tp[0] = a0; tp[64] = a1; tp[128] = a2; tp[192] = a3;
    } else {
        if (n     < N) T[(size_t)(n    ) * 64 + lane] = a0;
        if (n + 1 < N) T[(size_t)(n + 1) * 64 + lane] = a1;
        if (n + 2 < N) T[(size_t)(n + 2) * 64 + lane] = a2;
        if (n + 3 < N) T[(size_t)(n + 3) * 64 + lane] = a3;
    }
}

// ---------------- aggregation (float4, 4 nodes/wave) ----------------
#define AGG_RELU 1
#define AGG_IDENT 2
__global__ __launch_bounds__(256) void agg_kernel(const float* __restrict__ T, const unsigned long long* __restrict__ csr,
                                                  const int* __restrict__ rowstart, const float* __restrict__ dis2,
                                                  const float* __restrict__ b, const float* __restrict__ identity,
                                                  float* __restrict__ out, int N, int flags) {
    int c  = threadIdx.x & 15;
    int g  = (threadIdx.x >> 4) & 3;
    int wv = threadIdx.x >> 6;
    float4 bv = *(const float4*)(b + 4 * c);
    for (int n0 = blockIdx.x * 16; n0 < N; n0 += gridDim.x * 16) {
        int n = n0 + wv * 4 + g;
        if (n < N) {
            float4 acc = *(const float4*)(T + (size_t)n * 64 + 4 * c);
            float d2 = dis2[n];
            acc.x = acc.x * d2 + bv.x;
            acc.y = acc.y * d2 + bv.y;
            acc.z = acc.z * d2 + bv.z;
            acc.w = acc.w * d2 + bv.w;
            int e0 = rowstart[n], e1 = rowstart[n + 1];
            for (int e = e0; e < e1; e++) {
                unsigned long long pk = csr[e];
                int s   = (int)(unsigned int)(pk & 0xFFFFFFFFull);
                float w = __uint_as_float((unsigned int)(pk >> 32));
                float4 v = *(const float4*)(T + (size_t)s * 64 + 4 * c);
                acc.x += w * v.x;
                acc.y += w * v.y;
                acc.z += w * v.z;
                acc.w += w * v.w;
            }
            if (flags & AGG_IDENT) {
                float4 iv = *(const float4*)(identity + (size_t)n * 64 + 4 * c);
                acc.x += iv.x; acc.y += iv.y; acc.z += iv.z; acc.w += iv.w;
            }
            if (flags & AGG_RELU) {
                acc.x = fmaxf(acc.x, 0.0f);
                acc.y = fmaxf(acc.y, 0.0f);
                acc.z = fmaxf(acc.z, 0.0f);
                acc.w = fmaxf(acc.w, 0.0f);
            }
            *(float4*)(out + (size_t)n * 64 + 4 * c) = acc;
        }
    }
}

// ---------------- s = softmax(out @ Wl + bl); den += deg[n]*sum(s^2)
// out rows staged in LDS via coalesced float4 (was: 64 broadcast scalar loads/node)
__global__ __launch_bounds__(256) void slogits_kernel(const float* __restrict__ out, const float* __restrict__ Wl,
                                                      const float* __restrict__ bl, const int* __restrict__ deg,
                                                      float* __restrict__ s, float* __restrict__ accum, int N) {
    __shared__ float w[64 * 16];
    __shared__ float bs[16];
    __shared__ float tile[16][68];
    __shared__ float red[16];
    for (int i = threadIdx.x; i < 1024; i += 256) w[i] = Wl[i];
    if (threadIdx.x < 16) bs[threadIdx.x] = bl[threadIdx.x];
    int n0 = blockIdx.x * 16;
    {
        int row = threadIdx.x >> 4, e4 = threadIdx.x & 15;
        int n = n0 + row;
        float4 v = make_float4(0.f, 0.f, 0.f, 0.f);
        if (n < N) v = *(const float4*)(out + (size_t)n * 64 + e4 * 4);
        *(float4*)&tile[row][e4 * 4] = v;
    }
    __syncthreads();
    int k = threadIdx.x & 15, grp = threadIdx.x >> 4;
    int n = n0 + grp;
    float denpart = 0.0f;
    if (n < N) {
        float acc = bs[k];
        #pragma unroll
        for (int j = 0; j < 64; j++) acc += tile[grp][j] * w[j * 16 + k];
        float m = acc;
        for (int off = 8; off; off >>= 1) m = fmaxf(m, __shfl_xor(m, off, 16));
        float e = __expf(acc - m);
        float sum = e;
        for (int off = 8; off; off >>= 1) sum += __shfl_xor(sum, off, 16);
        float sv = e / sum;
        s[(size_t)n * 16 + k] = sv;
        float ssum = sv * sv;
        for (int off = 8; off; off >>= 1) ssum += __shfl_xor(ssum, off, 16);
        if (k == 0) denpart = (float)deg[n] * ssum;
    }
    if (k == 0) red[grp] = denpart;
    __syncthreads();
    if (threadIdx.x == 0) {
        float tot = 0.f;
        for (int i = 0; i < 16; i++) tot += red[i];
        atomicAdd(&accum[1], tot);
    }
}

// ---------------- ss = s^T @ s (16x16), accumulated ----------------
__global__ __launch_bounds__(256) void sst_kernel(const float* __restrict__ s, int N, float* __restrict__ accum) {
    __shared__ float tile[256 * 16];
    int a = threadIdx.x >> 4, b = threadIdx.x & 15;
    float acc = 0.0f;
    for (int base = blockIdx.x * 256; base < N; base += gridDim.x * 256) {
        int cnt = min(256, N - base);
        for (int i = threadIdx.x; i < cnt * 16; i += 256) tile[i] = s[(size_t)base * 16 + i];
        __syncthreads();
        for (int i = 0; i < cnt; i++) acc += tile[i * 16 + a] * tile[i * 16 + b];
        __syncthreads();
    }
    atomicAdd(&accum[2 + threadIdx.x], acc);
}

// ---------------- num = sum_e sum_k s[src][k]*s[dst][k] ----------------
__global__ __launch_bounds__(256) void num_kernel(const int* __restrict__ src, const int* __restrict__ dst,
                                                  const float* __restrict__ s, int E, float* __restrict__ accum) {
    int k = threadIdx.x & 15, grp = threadIdx.x >> 4;
    float acc = 0.0f;
    for (int e = blockIdx.x * 16 + grp; e < E; e += gridDim.x * 16) {
        int a = src[e], b = dst[e];
        acc += s[(size_t)a * 16 + k] * s[(size_t)b * 16 + k];
    }
    __shared__ float red[256];
    red[threadIdx.x] = acc;
    __syncthreads();
    for (int off = 128; off; off >>= 1) {
        if (threadIdx.x < off) red[threadIdx.x] += red[threadIdx.x + off];
        __syncthreads();
    }
    if (threadIdx.x == 0) atomicAdd(&accum[0], red[0]);
}

// ---------------- final: mc = -(num/den); o = ||ss/||ss|| - I/4||_F ----------------
__global__ __launch_bounds__(256) void final_kernel(const float* __restrict__ accum, float* __restrict__ out) {
    __shared__ float red[256];
    __shared__ float nrm_s;
    int t = threadIdx.x;
    float v = accum[2 + t];
    red[t] = v * v;
    __syncthreads();
    for (int off = 128; off; off >>= 1) {
        if (t < off) red[t] += red[t + off];
        __syncthreads();
    }
    if (t == 0) nrm_s = sqrtf(red[0]);
    __syncthreads();
    float d = v / nrm_s - (((t % 17) == 0) ? 0.25f : 0.0f);
    red[t] = d * d;
    __syncthreads();
    for (int off = 128; off; off >>= 1) {
        if (t < off) red[t] += red[t + off];
        __syncthreads();
    }
    if (t == 0) {
        out[0] = -(accum[0] / accum[1]);
        out[1] = sqrtf(red[0]);
    }
}

extern "C" void kernel_launch(void* const* d_in, const int* in_sizes, int n_in,
                              void* d_out, int out_size, void* d_ws, size_t ws_size,
                              hipStream_t stream) {
    const float* x  = (const float*)d_in[0];
    const int*   ei = (const int*)d_in[1];
    const float* W0 = (const float*)d_in[4];
    const float* b0 = (const float*)d_in[5];
    const float* W1 = (const float*)d_in[6];
    const float* b1 = (const float*)d_in[7];
    const float* W2 = (const float*)d_in[8];
    const float* b2 = (const float*)d_in[9];
    const float* W3 = (const float*)d_in[10];
    const float* b3 = (const float*)d_in[11];
    const float* Wl = (const float*)d_in[12];
    const float* bl = (const float*)d_in[13];
    float* outp = (float*)d_out;

    int N = in_sizes[0] / 41;   // x: (N, 1+2G) = (N, 41)
    int E = in_sizes[1] / 2;    // edge_index: (2, E)
    const int* src = ei;
    const int* dst = ei + E;

    int nsb = (N + 255) / 256;         // scan blocks (196 for N=50k)

    // workspace layout
    char* p = (char*)d_ws;
    float* accum   = (float*)p;                 p += WSA(260 * 4);          // [0]=num [1]=den [2..257]=ss
    int*   deg     = (int*)p;                   p += WSA((size_t)N * 4);
    int*   rowstart= (int*)p;                   p += WSA((size_t)(N + 1) * 4);
    int*   cursor  = (int*)p;                   p += WSA((size_t)N * 4);
    float* dis     = (float*)p;                 p += WSA((size_t)N * 4);
    float* dis2    = (float*)p;                 p += WSA((size_t)N * 4);
    int*   blocksum= (int*)p;                   p += WSA((size_t)nsb * 4);
    int*   blockoff= (int*)p;                   p += WSA((size_t)nsb * 4);
    unsigned long long* csr = (unsigned long long*)p; p += WSA((size_t)E * 8);
    float* ident   = (float*)p;                 p += WSA((size_t)N * 64 * 4);
    float* bufA    = (float*)p;                 p += WSA((size_t)N * 64 * 4);
    float* bufB    = (float*)p;                 p += WSA((size_t)N * 64 * 4);
    float* sbuf    = (float*)p;                 p += WSA((size_t)N * 16 * 4);

    int h0blk    = (N + 3) / 4;        // 4 nodes per block (h0: 1 node/wave, LDS-staged)
    int aggblk   = (N + 15) / 16;      // 16 nodes per block (agg: 4 nodes/wave)
    int gemmblk  = (N + 15) / 16;      // 16 rows per block (LDS-staged)
    int grpblk   = (N + 15) / 16;      // 16 nodes per block (slogits, LDS-staged)
    int tileblk  = (N + 255) / 256;

    zero_kernel<<<(N + 255) / 256, 256, 0, stream>>>(deg, accum, N);
    deg_kernel<<<2048, 256, 0, stream>>>(dst, E, deg);
    // hierarchical scan
    partial_kernel<<<nsb, 256, 0, stream>>>(deg, N, blocksum);
    scanblocks_kernel<<<1, 1024, 0, stream>>>(blocksum, nsb, blockoff);
    fillrow_kernel<<<nsb, 256, 0, stream>>>(deg, blockoff, N, E, rowstart, cursor, dis, dis2);
    fill_kernel<<<2048, 256, 0, stream>>>(src, dst, E, cursor, dis, csr);

    // layer 0 (h0 = identity)
    h0_kernel<<<h0blk, 256, 0, stream>>>(x, W0, b0, ident, N);

    // layer 1: T = ident @ W1 -> bufA ; agg -> bufB (relu)
    gemm64_kernel<<<gemmblk, 256, 0, stream>>>(ident, W1, bufA, N);
    agg_kernel<<<aggblk, 256, 0, stream>>>(bufA, csr, rowstart, dis2, b1, ident, bufB, N, AGG_RELU);

    // layer 2: T = bufB @ W2 -> bufA ; agg -> bufB (relu)
    gemm64_kernel<<<gemmblk, 256, 0, stream>>>(bufB, W2, bufA, N);
    agg_kernel<<<aggblk, 256, 0, stream>>>(bufA, csr, rowstart, dis2, b2, ident, bufB, N, AGG_RELU);

    // layer 3: T = bufB @ W3 -> bufA ; agg + identity -> bufB (relu)
    gemm64_kernel<<<gemmblk, 256, 0, stream>>>(bufB, W3, bufA, N);
    agg_kernel<<<aggblk, 256, 0, stream>>>(bufA, csr, rowstart, dis2, b3, ident, bufB, N, AGG_RELU | AGG_IDENT);

    // losses
    slogits_kernel<<<grpblk, 256, 0, stream>>>(bufB, Wl, bl, deg, sbuf, accum, N);
    sst_kernel<<<tileblk, 256, 0, stream>>>(sbuf, N, accum);
    num_kernel<<<2048, 256, 0, stream>>>(src, dst, sbuf, E, accum);
    final_kernel<<<1, 256, 0, stream>>>(accum, outp);
}

// Round 15
// 452.994 us; speedup vs baseline: 1.4962x; 1.0315x over previous
//
#include <hip/hip_runtime.h>
#include <hip/hip_bf16.h>
#include <math.h>

#define WSA(x) (((x) + 255) & ~(size_t)255)
#define NB_SLG 512   // slogits blocks (= den partials)
#define NB_NUM 512   // num blocks (= num partials)
#define NB_SST 64    // sst blocks (= ss partial rows)

// ---------------- zero init (re-poisoned ws each call) ----------------
__global__ void zero_kernel(int* __restrict__ deg, int N) {
    int i = blockIdx.x * blockDim.x + threadIdx.x;
    if (i < N) deg[i] = 0;
}

// ---------------- degree histogram ----------------
__global__ void deg_kernel(const int* __restrict__ dst, int E, int* __restrict__ deg) {
    for (int i = blockIdx.x * blockDim.x + threadIdx.x; i < E; i += gridDim.x * blockDim.x)
        atomicAdd(&deg[dst[i]], 1);
}

// ---------------- hierarchical scan, stage 1: per-block sums of deg ----------------
__global__ __launch_bounds__(256) void partial_kernel(const int* __restrict__ deg, int N,
                                                      int* __restrict__ blocksum) {
    __shared__ int sh[256];
    int t = threadIdx.x;
    int i = blockIdx.x * 256 + t;
    sh[t] = (i < N) ? deg[i] : 0;
    __syncthreads();
    for (int off = 128; off; off >>= 1) {
        if (t < off) sh[t] += sh[t + off];
        __syncthreads();
    }
    if (t == 0) blocksum[blockIdx.x] = sh[0];
}

// ---------------- stage 2: exclusive scan of block sums (single block) ----------------
__global__ __launch_bounds__(1024) void scanblocks_kernel(const int* __restrict__ blocksum,
                                                          int nsb, int* __restrict__ blockoff) {
    __shared__ int part[1024];
    int t = threadIdx.x;
    part[t] = (t < nsb) ? blocksum[t] : 0;
    __syncthreads();
    for (int off = 1; off < 1024; off <<= 1) {
        int v = 0;
        if (t >= off) v = part[t - off];
        __syncthreads();
        if (t >= off) part[t] += v;
        __syncthreads();
    }
    if (t < nsb) blockoff[t] = (t == 0) ? 0 : part[t - 1];
}

// ---------------- stage 3: in-block scan + rowstart/cursor/dis/dis2 fill ----------------
__global__ __launch_bounds__(256) void fillrow_kernel(const int* __restrict__ deg, const int* __restrict__ blockoff,
                                                      int N, int E, int* __restrict__ rowstart,
                                                      int* __restrict__ cursor, float* __restrict__ dis,
                                                      float* __restrict__ dis2) {
    __shared__ int sh[256];
    int t = threadIdx.x;
    int i = blockIdx.x * 256 + t;
    int d = (i < N) ? deg[i] : 0;
    sh[t] = d;
    __syncthreads();
    for (int off = 1; off < 256; off <<= 1) {
        int v = 0;
        if (t >= off) v = sh[t - off];
        __syncthreads();
        if (t >= off) sh[t] += v;
        __syncthreads();
    }
    if (i < N) {
        int run = blockoff[blockIdx.x] + ((t == 0) ? 0 : sh[t - 1]);
        rowstart[i] = run;
        cursor[i] = run;
        float df = (float)d + 1.0f;
        dis[i]  = rsqrtf(df);
        dis2[i] = 1.0f / df;
    }
    if (i == 0) rowstart[N] = E;
}

// ---------------- CSR fill: pack {src, w=dis[src]*dis[dst]} ----------------
__global__ void fill_kernel(const int* __restrict__ src, const int* __restrict__ dst, int E,
                            int* __restrict__ cursor, const float* __restrict__ dis,
                            unsigned long long* __restrict__ csr) {
    for (int i = blockIdx.x * blockDim.x + threadIdx.x; i < E; i += gridDim.x * blockDim.x) {
        int s = src[i], d = dst[i];
        int pos = atomicAdd(&cursor[d], 1);
        float w = dis[s] * dis[d];
        unsigned long long pk = ((unsigned long long)__float_as_uint(w) << 32) | (unsigned int)s;
        csr[pos] = pk;
    }
}

// ---------------- layer 0: h0 = relu(concat(onehot, x02) @ W0 + b0) ----------------
__global__ __launch_bounds__(256) void h0_kernel(const float* __restrict__ x, const float* __restrict__ W0,
                                                 const float* __restrict__ b0, float* __restrict__ h0, int N) {
    __shared__ float w[60 * 64];
    __shared__ float bs[64];
    __shared__ float xs[4 * 41];
    for (int i = threadIdx.x; i < 60 * 64; i += 256) w[i] = W0[i];
    if (threadIdx.x < 64) bs[threadIdx.x] = b0[threadIdx.x];
    int n0 = blockIdx.x * 4;
    {
        int base = n0 * 41;
        int avail = N * 41 - base;
        int cnt = (avail < 4 * 41) ? avail : (4 * 41);
        if ((int)threadIdx.x < cnt) xs[threadIdx.x] = x[(size_t)base + threadIdx.x];
    }
    __syncthreads();
    int lane = threadIdx.x & 63, wv = threadIdx.x >> 6;
    int n = n0 + wv;
    if (n < N) {
        const float* xr = xs + wv * 41;
        int ct = (int)xr[0];
        float acc = w[ct * 64 + lane] + bs[lane];
        #pragma unroll
        for (int j = 0; j < 40; j++) acc += xr[1 + j] * w[(20 + j) * 64 + lane];
        h0[(size_t)n * 64 + lane] = fmaxf(acc, 0.0f);
    }
}

// ---------------- T = H @ W (H: N x 64, W: 64 x 64), LDS-staged ----------------
__global__ __launch_bounds__(256) void gemm64_kernel(const float* __restrict__ H, const float* __restrict__ W,
                                                     float* __restrict__ T, int N) {
    __shared__ float w[64 * 64];
    __shared__ float tile[16][68];
    for (int i = threadIdx.x; i < 4096; i += 256) w[i] = W[i];
    int n0 = blockIdx.x * 16;
    {
        int row = threadIdx.x >> 4, e4 = threadIdx.x & 15;
        int n = n0 + row;
        float4 v = make_float4(0.f, 0.f, 0.f, 0.f);
        if (n < N) v = *(const float4*)(H + (size_t)n * 64 + e4 * 4);
        *(float4*)&tile[row][e4 * 4] = v;
    }
    __syncthreads();
    int lane = threadIdx.x & 63, wv = threadIdx.x >> 6;
    int r0 = wv * 4;
    float a0 = 0.f, a1 = 0.f, a2 = 0.f, a3 = 0.f;
    #pragma unroll
    for (int k = 0; k < 64; k++) {
        float wk = w[k * 64 + lane];
        a0 += tile[r0 + 0][k] * wk;
        a1 += tile[r0 + 1][k] * wk;
        a2 += tile[r0 + 2][k] * wk;
        a3 += tile[r0 + 3][k] * wk;
    }
    int n = n0 + r0;
    if (n + 3 < N) {
        float* tp = T + (size_t)n * 64 + lane;
        tp[0] = a0; tp[64] = a1; tp[128] = a2; tp[192] = a3;
    } else {
        if (n     < N) T[(size_t)(n    ) * 64 + lane] = a0;
        if (n + 1 < N) T[(size_t)(n + 1) * 64 + lane] = a1;
        if (n + 2 < N) T[(size_t)(n + 2) * 64 + lane] = a2;
        if (n + 3 < N) T[(size_t)(n + 3) * 64 + lane] = a3;
    }
}

// ---------------- aggregation (float4, 4 nodes/wave) ----------------
#define AGG_RELU 1
#define AGG_IDENT 2
__global__ __launch_bounds__(256) void agg_kernel(const float* __restrict__ T, const unsigned long long* __restrict__ csr,
                                                  const int* __restrict__ rowstart, const float* __restrict__ dis2,
                                                  const float* __restrict__ b, const float* __restrict__ identity,
                                                  float* __restrict__ out, int N, int flags) {
    int c  = threadIdx.x & 15;
    int g  = (threadIdx.x >> 4) & 3;
    int wv = threadIdx.x >> 6;
    float4 bv = *(const float4*)(b + 4 * c);
    for (int n0 = blockIdx.x * 16; n0 < N; n0 += gridDim.x * 16) {
        int n = n0 + wv * 4 + g;
        if (n < N) {
            float4 acc = *(const float4*)(T + (size_t)n * 64 + 4 * c);
            float d2 = dis2[n];
            acc.x = acc.x * d2 + bv.x;
            acc.y = acc.y * d2 + bv.y;
            acc.z = acc.z * d2 + bv.z;
            acc.w = acc.w * d2 + bv.w;
            int e0 = rowstart[n], e1 = rowstart[n + 1];
            for (int e = e0; e < e1; e++) {
                unsigned long long pk = csr[e];
                int s   = (int)(unsigned int)(pk & 0xFFFFFFFFull);
                float w = __uint_as_float((unsigned int)(pk >> 32));
                float4 v = *(const float4*)(T + (size_t)s * 64 + 4 * c);
                acc.x += w * v.x;
                acc.y += w * v.y;
                acc.z += w * v.z;
                acc.w += w * v.w;
            }
            if (flags & AGG_IDENT) {
                float4 iv = *(const float4*)(identity + (size_t)n * 64 + 4 * c);
                acc.x += iv.x; acc.y += iv.y; acc.z += iv.z; acc.w += iv.w;
            }
            if (flags & AGG_RELU) {
                acc.x = fmaxf(acc.x, 0.0f);
                acc.y = fmaxf(acc.y, 0.0f);
                acc.z = fmaxf(acc.z, 0.0f);
                acc.w = fmaxf(acc.w, 0.0f);
            }
            *(float4*)(out + (size_t)n * 64 + 4 * c) = acc;
        }
    }
}

// ---------------- s = softmax(out @ Wl + bl); den partial per block (NO atomic) ----------------
__global__ __launch_bounds__(256) void slogits_kernel(const float* __restrict__ out, const float* __restrict__ Wl,
                                                      const float* __restrict__ bl, const int* __restrict__ deg,
                                                      float* __restrict__ s, float* __restrict__ den_part, int N) {
    __shared__ float w[64 * 16];
    __shared__ float bs[16];
    __shared__ float tile[16][68];
    __shared__ float red[16];
    for (int i = threadIdx.x; i < 1024; i += 256) w[i] = Wl[i];
    if (threadIdx.x < 16) bs[threadIdx.x] = bl[threadIdx.x];
    int k = threadIdx.x & 15, grp = threadIdx.x >> 4;
    int row = threadIdx.x >> 4, e4 = threadIdx.x & 15;
    float denpart = 0.0f;
    __syncthreads();
    for (int n0 = blockIdx.x * 16; n0 < N; n0 += gridDim.x * 16) {
        int sn = n0 + row;
        float4 v = make_float4(0.f, 0.f, 0.f, 0.f);
        if (sn < N) v = *(const float4*)(out + (size_t)sn * 64 + e4 * 4);
        *(float4*)&tile[row][e4 * 4] = v;
        __syncthreads();
        int n = n0 + grp;
        if (n < N) {
            float acc = bs[k];
            #pragma unroll
            for (int j = 0; j < 64; j++) acc += tile[grp][j] * w[j * 16 + k];
            float m = acc;
            for (int off = 8; off; off >>= 1) m = fmaxf(m, __shfl_xor(m, off, 16));
            float e = __expf(acc - m);
            float sum = e;
            for (int off = 8; off; off >>= 1) sum += __shfl_xor(sum, off, 16);
            float sv = e / sum;
            s[(size_t)n * 16 + k] = sv;
            float ssum = sv * sv;
            for (int off = 8; off; off >>= 1) ssum += __shfl_xor(ssum, off, 16);
            if (k == 0) denpart += (float)deg[n] * ssum;
        }
        __syncthreads();
    }
    if (k == 0) red[grp] = denpart;
    __syncthreads();
    if (threadIdx.x == 0) {
        float tot = 0.f;
        for (int i = 0; i < 16; i++) tot += red[i];
        den_part[blockIdx.x] = tot;
    }
}

// ---------------- ss partials: each thread stores its (a,b) entry partial (NO atomic) ----------------
__global__ __launch_bounds__(256) void sst_kernel(const float* __restrict__ s, int N, float* __restrict__ ss_part) {
    __shared__ float tile[256 * 16];
    int a = threadIdx.x >> 4, b = threadIdx.x & 15;
    float acc = 0.0f;
    for (int base = blockIdx.x * 256; base < N; base += gridDim.x * 256) {
        int cnt = min(256, N - base);
        for (int i = threadIdx.x; i < cnt * 16; i += 256) tile[i] = s[(size_t)base * 16 + i];
        __syncthreads();
        for (int i = 0; i < cnt; i++) acc += tile[i * 16 + a] * tile[i * 16 + b];
        __syncthreads();
    }
    ss_part[(size_t)blockIdx.x * 256 + threadIdx.x] = acc;
}

// ---------------- num partials per block (NO atomic) ----------------
__global__ __launch_bounds__(256) void num_kernel(const int* __restrict__ src, const int* __restrict__ dst,
                                                  const float* __restrict__ s, int E, float* __restrict__ num_part) {
    int k = threadIdx.x & 15, grp = threadIdx.x >> 4;
    float acc = 0.0f;
    for (int e = blockIdx.x * 16 + grp; e < E; e += gridDim.x * 16) {
        int a = src[e], b = dst[e];
        acc += s[(size_t)a * 16 + k] * s[(size_t)b * 16 + k];
    }
    __shared__ float red[256];
    red[threadIdx.x] = acc;
    __syncthreads();
    for (int off = 128; off; off >>= 1) {
        if (threadIdx.x < off) red[threadIdx.x] += red[threadIdx.x + off];
        __syncthreads();
    }
    if (threadIdx.x == 0) num_part[blockIdx.x] = red[0];
}

// ---------------- final: reduce partials; mc = -(num/den); o = ||ss/||ss|| - I/4||_F ----------------
__global__ __launch_bounds__(256) void final_kernel(const float* __restrict__ num_part, const float* __restrict__ den_part,
                                                    const float* __restrict__ ss_part, float* __restrict__ out) {
    __shared__ float redn[256];
    __shared__ float redd[256];
    __shared__ float red[256];
    __shared__ float nrm_s;
    int t = threadIdx.x;
    float ns = 0.f, ds = 0.f;
    for (int i = t; i < NB_NUM; i += 256) ns += num_part[i];
    for (int i = t; i < NB_SLG; i += 256) ds += den_part[i];
    redn[t] = ns; redd[t] = ds;
    float v = 0.f;
    for (int b = 0; b < NB_SST; b++) v += ss_part[(size_t)b * 256 + t];
    red[t] = v * v;
    __syncthreads();
    for (int off = 128; off; off >>= 1) {
        if (t < off) { redn[t] += redn[t + off]; redd[t] += redd[t + off]; red[t] += red[t + off]; }
        __syncthreads();
    }
    if (t == 0) nrm_s = sqrtf(red[0]);
    __syncthreads();
    float d = v / nrm_s - (((t % 17) == 0) ? 0.25f : 0.0f);
    red[t] = d * d;
    __syncthreads();
    for (int off = 128; off; off >>= 1) {
        if (t < off) red[t] += red[t + off];
        __syncthreads();
    }
    if (t == 0) {
        out[0] = -(redn[0] / redd[0]);
        out[1] = sqrtf(red[0]);
    }
}

extern "C" void kernel_launch(void* const* d_in, const int* in_sizes, int n_in,
                              void* d_out, int out_size, void* d_ws, size_t ws_size,
                              hipStream_t stream) {
    const float* x  = (const float*)d_in[0];
    const int*   ei = (const int*)d_in[1];
    const float* W0 = (const float*)d_in[4];
    const float* b0 = (const float*)d_in[5];
    const float* W1 = (const float*)d_in[6];
    const float* b1 = (const float*)d_in[7];
    const float* W2 = (const float*)d_in[8];
    const float* b2 = (const float*)d_in[9];
    const float* W3 = (const float*)d_in[10];
    const float* b3 = (const float*)d_in[11];
    const float* Wl = (const float*)d_in[12];
    const float* bl = (const float*)d_in[13];
    float* outp = (float*)d_out;

    int N = in_sizes[0] / 41;   // x: (N, 1+2G) = (N, 41)
    int E = in_sizes[1] / 2;    // edge_index: (2, E)
    const int* src = ei;
    const int* dst = ei + E;

    int nsb = (N + 255) / 256;         // scan blocks (196 for N=50k)

    // workspace layout
    char* p = (char*)d_ws;
    int*   deg     = (int*)p;                   p += WSA((size_t)N * 4);
    int*   rowstart= (int*)p;                   p += WSA((size_t)(N + 1) * 4);
    int*   cursor  = (int*)p;                   p += WSA((size_t)N * 4);
    float* dis     = (float*)p;                 p += WSA((size_t)N * 4);
    float* dis2    = (float*)p;                 p += WSA((size_t)N * 4);
    int*   blocksum= (int*)p;                   p += WSA((size_t)nsb * 4);
    int*   blockoff= (int*)p;                   p += WSA((size_t)nsb * 4);
    float* den_part= (float*)p;                 p += WSA((size_t)NB_SLG * 4);
    float* num_part= (float*)p;                 p += WSA((size_t)NB_NUM * 4);
    float* ss_part = (float*)p;                 p += WSA((size_t)NB_SST * 256 * 4);
    unsigned long long* csr = (unsigned long long*)p; p += WSA((size_t)E * 8);
    float* ident   = (float*)p;                 p += WSA((size_t)N * 64 * 4);
    float* bufA    = (float*)p;                 p += WSA((size_t)N * 64 * 4);
    float* bufB    = (float*)p;                 p += WSA((size_t)N * 64 * 4);
    float* sbuf    = (float*)p;                 p += WSA((size_t)N * 16 * 4);

    int h0blk    = (N + 3) / 4;
    int aggblk   = (N + 15) / 16;
    int gemmblk  = (N + 15) / 16;

    zero_kernel<<<(N + 255) / 256, 256, 0, stream>>>(deg, N);
    deg_kernel<<<2048, 256, 0, stream>>>(dst, E, deg);
    // hierarchical scan
    partial_kernel<<<nsb, 256, 0, stream>>>(deg, N, blocksum);
    scanblocks_kernel<<<1, 1024, 0, stream>>>(blocksum, nsb, blockoff);
    fillrow_kernel<<<nsb, 256, 0, stream>>>(deg, blockoff, N, E, rowstart, cursor, dis, dis2);
    fill_kernel<<<2048, 256, 0, stream>>>(src, dst, E, cursor, dis, csr);

    // layer 0 (h0 = identity)
    h0_kernel<<<h0blk, 256, 0, stream>>>(x, W0, b0, ident, N);

    // layer 1: T = ident @ W1 -> bufA ; agg -> bufB (relu)
    gemm64_kernel<<<gemmblk, 256, 0, stream>>>(ident, W1, bufA, N);
    agg_kernel<<<aggblk, 256, 0, stream>>>(bufA, csr, rowstart, dis2, b1, ident, bufB, N, AGG_RELU);

    // layer 2: T = bufB @ W2 -> bufA ; agg -> bufB (relu)
    gemm64_kernel<<<gemmblk, 256, 0, stream>>>(bufB, W2, bufA, N);
    agg_kernel<<<aggblk, 256, 0, stream>>>(bufA, csr, rowstart, dis2, b2, ident, bufB, N, AGG_RELU);

    // layer 3: T = bufB @ W3 -> bufA ; agg + identity -> bufB (relu)
    gemm64_kernel<<<gemmblk, 256, 0, stream>>>(bufB, W3, bufA, N);
    agg_kernel<<<aggblk, 256, 0, stream>>>(bufA, csr, rowstart, dis2, b3, ident, bufB, N, AGG_RELU | AGG_IDENT);

    // losses (atomic-free: per-block partials + final reduce)
    slogits_kernel<<<NB_SLG, 256, 0, stream>>>(bufB, Wl, bl, deg, sbuf, den_part, N);
    sst_kernel<<<NB_SST, 256, 0, stream>>>(sbuf, N, ss_part);
    num_kernel<<<NB_NUM, 256, 0, stream>>>(src, dst, sbuf, E, num_part);
    final_kernel<<<1, 256, 0, stream>>>(num_part, den_part, ss_part, outp);
}

// Round 17
// 421.568 us; speedup vs baseline: 1.6078x; 1.0745x over previous
//
#include <hip/hip_runtime.h>
#include <hip/hip_bf16.h>
#include <math.h>

#define WSA(x) (((x) + 255) & ~(size_t)255)
#define NB_SLG 512    // slogits blocks (= den partials)
#define NB_NUM 4096   // num blocks (= num partials) — latency-bound, needs TLP
#define NB_SST 64     // sst blocks (= ss partial rows)

// ---------------- zero init (re-poisoned ws each call) ----------------
__global__ void zero_kernel(int* __restrict__ deg, int N) {
    int i = blockIdx.x * blockDim.x + threadIdx.x;
    if (i < N) deg[i] = 0;
}

// ---------------- degree histogram ----------------
__global__ void deg_kernel(const int* __restrict__ dst, int E, int* __restrict__ deg) {
    for (int i = blockIdx.x * blockDim.x + threadIdx.x; i < E; i += gridDim.x * blockDim.x)
        atomicAdd(&deg[dst[i]], 1);
}

// ---------------- hierarchical scan, stage 1: per-block sums of deg ----------------
__global__ __launch_bounds__(256) void partial_kernel(const int* __restrict__ deg, int N,
                                                      int* __restrict__ blocksum) {
    __shared__ int sh[256];
    int t = threadIdx.x;
    int i = blockIdx.x * 256 + t;
    sh[t] = (i < N) ? deg[i] : 0;
    __syncthreads();
    for (int off = 128; off; off >>= 1) {
        if (t < off) sh[t] += sh[t + off];
        __syncthreads();
    }
    if (t == 0) blocksum[blockIdx.x] = sh[0];
}

// ---------------- stage 2: exclusive scan of block sums (single block) ----------------
__global__ __launch_bounds__(1024) void scanblocks_kernel(const int* __restrict__ blocksum,
                                                          int nsb, int* __restrict__ blockoff) {
    __shared__ int part[1024];
    int t = threadIdx.x;
    part[t] = (t < nsb) ? blocksum[t] : 0;
    __syncthreads();
    for (int off = 1; off < 1024; off <<= 1) {
        int v = 0;
        if (t >= off) v = part[t - off];
        __syncthreads();
        if (t >= off) part[t] += v;
        __syncthreads();
    }
    if (t < nsb) blockoff[t] = (t == 0) ? 0 : part[t - 1];
}

// ---------------- stage 3: in-block scan + rowstart/cursor/dis/dis2 fill ----------------
__global__ __launch_bounds__(256) void fillrow_kernel(const int* __restrict__ deg, const int* __restrict__ blockoff,
                                                      int N, int E, int* __restrict__ rowstart,
                                                      int* __restrict__ cursor, float* __restrict__ dis,
                                                      float* __restrict__ dis2) {
    __shared__ int sh[256];
    int t = threadIdx.x;
    int i = blockIdx.x * 256 + t;
    int d = (i < N) ? deg[i] : 0;
    sh[t] = d;
    __syncthreads();
    for (int off = 1; off < 256; off <<= 1) {
        int v = 0;
        if (t >= off) v = sh[t - off];
        __syncthreads();
        if (t >= off) sh[t] += v;
        __syncthreads();
    }
    if (i < N) {
        int run = blockoff[blockIdx.x] + ((t == 0) ? 0 : sh[t - 1]);
        rowstart[i] = run;
        cursor[i] = run;
        float df = (float)d + 1.0f;
        dis[i]  = rsqrtf(df);
        dis2[i] = 1.0f / df;
    }
    if (i == 0) rowstart[N] = E;
}

// ---------------- CSR fill: pack {src, w=dis[src]*dis[dst]} ----------------
__global__ void fill_kernel(const int* __restrict__ src, const int* __restrict__ dst, int E,
                            int* __restrict__ cursor, const float* __restrict__ dis,
                            unsigned long long* __restrict__ csr) {
    for (int i = blockIdx.x * blockDim.x + threadIdx.x; i < E; i += gridDim.x * blockDim.x) {
        int s = src[i], d = dst[i];
        int pos = atomicAdd(&cursor[d], 1);
        float w = dis[s] * dis[d];
        unsigned long long pk = ((unsigned long long)__float_as_uint(w) << 32) | (unsigned int)s;
        csr[pos] = pk;
    }
}

// ---------------- layer 0: h0 = relu(concat(onehot, x02) @ W0 + b0) ----------------
__global__ __launch_bounds__(256) void h0_kernel(const float* __restrict__ x, const float* __restrict__ W0,
                                                 const float* __restrict__ b0, float* __restrict__ h0, int N) {
    __shared__ float w[60 * 64];
    __shared__ float bs[64];
    __shared__ float xs[4 * 41];
    for (int i = threadIdx.x; i < 60 * 64; i += 256) w[i] = W0[i];
    if (threadIdx.x < 64) bs[threadIdx.x] = b0[threadIdx.x];
    int n0 = blockIdx.x * 4;
    {
        int base = n0 * 41;
        int avail = N * 41 - base;
        int cnt = (avail < 4 * 41) ? avail : (4 * 41);
        if ((int)threadIdx.x < cnt) xs[threadIdx.x] = x[(size_t)base + threadIdx.x];
    }
    __syncthreads();
    int lane = threadIdx.x & 63, wv = threadIdx.x >> 6;
    int n = n0 + wv;
    if (n < N) {
        const float* xr = xs + wv * 41;
        int ct = (int)xr[0];
        float acc = w[ct * 64 + lane] + bs[lane];
        #pragma unroll
        for (int j = 0; j < 40; j++) acc += xr[1 + j] * w[(20 + j) * 64 + lane];
        h0[(size_t)n * 64 + lane] = fmaxf(acc, 0.0f);
    }
}

// ---------------- T = H @ W (H: N x 64, W: 64 x 64), LDS-staged ----------------
__global__ __launch_bounds__(256) void gemm64_kernel(const float* __restrict__ H, const float* __restrict__ W,
                                                     float* __restrict__ T, int N) {
    __shared__ float w[64 * 64];
    __shared__ float tile[16][68];
    for (int i = threadIdx.x; i < 4096; i += 256) w[i] = W[i];
    int n0 = blockIdx.x * 16;
    {
        int row = threadIdx.x >> 4, e4 = threadIdx.x & 15;
        int n = n0 + row;
        float4 v = make_float4(0.f, 0.f, 0.f, 0.f);
        if (n < N) v = *(const float4*)(H + (size_t)n * 64 + e4 * 4);
        *(float4*)&tile[row][e4 * 4] = v;
    }
    __syncthreads();
    int lane = threadIdx.x & 63, wv = threadIdx.x >> 6;
    int r0 = wv * 4;
    float a0 = 0.f, a1 = 0.f, a2 = 0.f, a3 = 0.f;
    #pragma unroll
    for (int k = 0; k < 64; k++) {
        float wk = w[k * 64 + lane];
        a0 += tile[r0 + 0][k] * wk;
        a1 += tile[r0 + 1][k] * wk;
        a2 += tile[r0 + 2][k] * wk;
        a3 += tile[r0 + 3][k] * wk;
    }
    int n = n0 + r0;
    if (n + 3 < N) {
        float* tp = T + (size_t)n * 64 + lane;
        tp[0] = a0; tp[64] = a1; tp[128] = a2; tp[192] = a3;
    } else {
        if (n     < N) T[(size_t)(n    ) * 64 + lane] = a0;
        if (n + 1 < N) T[(size_t)(n + 1) * 64 + lane] = a1;
        if (n + 2 < N) T[(size_t)(n + 2) * 64 + lane] = a2;
        if (n + 3 < N) T[(size_t)(n + 3) * 64 + lane] = a3;
    }
}

// ---------------- aggregation (float4, 4 nodes/wave) ----------------
#define AGG_RELU 1
#define AGG_IDENT 2
__global__ __launch_bounds__(256) void agg_kernel(const float* __restrict__ T, const unsigned long long* __restrict__ csr,
                                                  const int* __restrict__ rowstart, const float* __restrict__ dis2,
                                                  const float* __restrict__ b, const float* __restrict__ identity,
                                                  float* __restrict__ out, int N, int flags) {
    int c  = threadIdx.x & 15;
    int g  = (threadIdx.x >> 4) & 3;
    int wv = threadIdx.x >> 6;
    float4 bv = *(const float4*)(b + 4 * c);
    for (int n0 = blockIdx.x * 16; n0 < N; n0 += gridDim.x * 16) {
        int n = n0 + wv * 4 + g;
        if (n < N) {
            float4 acc = *(const float4*)(T + (size_t)n * 64 + 4 * c);
            float d2 = dis2[n];
            acc.x = acc.x * d2 + bv.x;
            acc.y = acc.y * d2 + bv.y;
            acc.z = acc.z * d2 + bv.z;
            acc.w = acc.w * d2 + bv.w;
            int e0 = rowstart[n], e1 = rowstart[n + 1];
            for (int e = e0; e < e1; e++) {
                unsigned long long pk = csr[e];
                int s   = (int)(unsigned int)(pk & 0xFFFFFFFFull);
                float w = __uint_as_float((unsigned int)(pk >> 32));
                float4 v = *(const float4*)(T + (size_t)s * 64 + 4 * c);
                acc.x += w * v.x;
                acc.y += w * v.y;
                acc.z += w * v.z;
                acc.w += w * v.w;
            }
            if (flags & AGG_IDENT) {
                float4 iv = *(const float4*)(identity + (size_t)n * 64 + 4 * c);
                acc.x += iv.x; acc.y += iv.y; acc.z += iv.z; acc.w += iv.w;
            }
            if (flags & AGG_RELU) {
                acc.x = fmaxf(acc.x, 0.0f);
                acc.y = fmaxf(acc.y, 0.0f);
                acc.z = fmaxf(acc.z, 0.0f);
                acc.w = fmaxf(acc.w, 0.0f);
            }
            *(float4*)(out + (size_t)n * 64 + 4 * c) = acc;
        }
    }
}

// ---------------- s = softmax(out @ Wl + bl); den partial per block (NO atomic) ----------------
__global__ __launch_bounds__(256) void slogits_kernel(const float* __restrict__ out, const float* __restrict__ Wl,
                                                      const float* __restrict__ bl, const int* __restrict__ deg,
                                                      float* __restrict__ s, float* __restrict__ den_part, int N) {
    __shared__ float w[64 * 16];
    __shared__ float bs[16];
    __shared__ float tile[16][68];
    __shared__ float red[16];
    for (int i = threadIdx.x; i < 1024; i += 256) w[i] = Wl[i];
    if (threadIdx.x < 16) bs[threadIdx.x] = bl[threadIdx.x];
    int k = threadIdx.x & 15, grp = threadIdx.x >> 4;
    int row = threadIdx.x >> 4, e4 = threadIdx.x & 15;
    float denpart = 0.0f;
    __syncthreads();
    for (int n0 = blockIdx.x * 16; n0 < N; n0 += gridDim.x * 16) {
        int sn = n0 + row;
        float4 v = make_float4(0.f, 0.f, 0.f, 0.f);
        if (sn < N) v = *(const float4*)(out + (size_t)sn * 64 + e4 * 4);
        *(float4*)&tile[row][e4 * 4] = v;
        __syncthreads();
        int n = n0 + grp;
        if (n < N) {
            float acc = bs[k];
            #pragma unroll
            for (int j = 0; j < 64; j++) acc += tile[grp][j] * w[j * 16 + k];
            float m = acc;
            for (int off = 8; off; off >>= 1) m = fmaxf(m, __shfl_xor(m, off, 16));
            float e = __expf(acc - m);
            float sum = e;
            for (int off = 8; off; off >>= 1) sum += __shfl_xor(sum, off, 16);
            float sv = e / sum;
            s[(size_t)n * 16 + k] = sv;
            float ssum = sv * sv;
            for (int off = 8; off; off >>= 1) ssum += __shfl_xor(ssum, off, 16);
            if (k == 0) denpart += (float)deg[n] * ssum;
        }
        __syncthreads();
    }
    if (k == 0) red[grp] = denpart;
    __syncthreads();
    if (threadIdx.x == 0) {
        float tot = 0.f;
        for (int i = 0; i < 16; i++) tot += red[i];
        den_part[blockIdx.x] = tot;
    }
}

// ---------------- ss partials: each thread stores its (a,b) entry partial (NO atomic) ----------------
__global__ __launch_bounds__(256) void sst_kernel(const float* __restrict__ s, int N, float* __restrict__ ss_part) {
    __shared__ float tile[256 * 16];
    int a = threadIdx.x >> 4, b = threadIdx.x & 15;
    float acc = 0.0f;
    for (int base = blockIdx.x * 256; base < N; base += gridDim.x * 256) {
        int cnt = min(256, N - base);
        for (int i = threadIdx.x; i < cnt * 16; i += 256) tile[i] = s[(size_t)base * 16 + i];
        __syncthreads();
        for (int i = 0; i < cnt; i++) acc += tile[i * 16 + a] * tile[i * 16 + b];
        __syncthreads();
    }
    ss_part[(size_t)blockIdx.x * 256 + threadIdx.x] = acc;
}

// ---------------- num partials per block (NO atomic; 2-way unrolled for MLP) ----------------
__global__ __launch_bounds__(256) void num_kernel(const int* __restrict__ src, const int* __restrict__ dst,
                                                  const float* __restrict__ s, int E, float* __restrict__ num_part) {
    int k = threadIdx.x & 15, grp = threadIdx.x >> 4;
    int stride = gridDim.x * 16;
    float acc0 = 0.0f, acc1 = 0.0f;
    int e = blockIdx.x * 16 + grp;
    for (; e + stride < E; e += 2 * stride) {
        int a0 = src[e],          b0 = dst[e];
        int a1 = src[e + stride], b1 = dst[e + stride];
        float s0a = s[(size_t)a0 * 16 + k];
        float s0b = s[(size_t)b0 * 16 + k];
        float s1a = s[(size_t)a1 * 16 + k];
        float s1b = s[(size_t)b1 * 16 + k];
        acc0 += s0a * s0b;
        acc1 += s1a * s1b;
    }
    if (e < E) {
        int a0 = src[e], b0 = dst[e];
        acc0 += s[(size_t)a0 * 16 + k] * s[(size_t)b0 * 16 + k];
    }
    __shared__ float red[256];
    red[threadIdx.x] = acc0 + acc1;
    __syncthreads();
    for (int off = 128; off; off >>= 1) {
        if (threadIdx.x < off) red[threadIdx.x] += red[threadIdx.x + off];
        __syncthreads();
    }
    if (threadIdx.x == 0) num_part[blockIdx.x] = red[0];
}

// ---------------- final: reduce partials; mc = -(num/den); o = ||ss/||ss|| - I/4||_F ----------------
__global__ __launch_bounds__(256) void final_kernel(const float* __restrict__ num_part, const float* __restrict__ den_part,
                                                    const float* __restrict__ ss_part, float* __restrict__ out) {
    __shared__ float redn[256];
    __shared__ float redd[256];
    __shared__ float red[256];
    __shared__ float nrm_s;
    int t = threadIdx.x;
    float ns = 0.f, ds = 0.f;
    for (int i = t; i < NB_NUM; i += 256) ns += num_part[i];
    for (int i = t; i < NB_SLG; i += 256) ds += den_part[i];
    redn[t] = ns; redd[t] = ds;
    float v = 0.f;
    for (int b = 0; b < NB_SST; b++) v += ss_part[(size_t)b * 256 + t];
    red[t] = v * v;
    __syncthreads();
    for (int off = 128; off; off >>= 1) {
        if (t < off) { redn[t] += redn[t + off]; redd[t] += redd[t + off]; red[t] += red[t + off]; }
        __syncthreads();
    }
    if (t == 0) nrm_s = sqrtf(red[0]);
    __syncthreads();
    float d = v / nrm_s - (((t % 17) == 0) ? 0.25f : 0.0f);
    red[t] = d * d;
    __syncthreads();
    for (int off = 128; off; off >>= 1) {
        if (t < off) red[t] += red[t + off];
        __syncthreads();
    }
    if (t == 0) {
        out[0] = -(redn[0] / redd[0]);
        out[1] = sqrtf(red[0]);
    }
}

extern "C" void kernel_launch(void* const* d_in, const int* in_sizes, int n_in,
                              void* d_out, int out_size, void* d_ws, size_t ws_size,
                              hipStream_t stream) {
    const float* x  = (const float*)d_in[0];
    const int*   ei = (const int*)d_in[1];
    const float* W0 = (const float*)d_in[4];
    const float* b0 = (const float*)d_in[5];
    const float* W1 = (const float*)d_in[6];
    const float* b1 = (const float*)d_in[7];
    const float* W2 = (const float*)d_in[8];
    const float* b2 = (const float*)d_in[9];
    const float* W3 = (const float*)d_in[10];
    const float* b3 = (const float*)d_in[11];
    const float* Wl = (const float*)d_in[12];
    const float* bl = (const float*)d_in[13];
    float* outp = (float*)d_out;

    int N = in_sizes[0] / 41;   // x: (N, 1+2G) = (N, 41)
    int E = in_sizes[1] / 2;    // edge_index: (2, E)
    const int* src = ei;
    const int* dst = ei + E;

    int nsb = (N + 255) / 256;         // scan blocks (196 for N=50k)

    // workspace layout
    char* p = (char*)d_ws;
    int*   deg     = (int*)p;                   p += WSA((size_t)N * 4);
    int*   rowstart= (int*)p;                   p += WSA((size_t)(N + 1) * 4);
    int*   cursor  = (int*)p;                   p += WSA((size_t)N * 4);
    float* dis     = (float*)p;                 p += WSA((size_t)N * 4);
    float* dis2    = (float*)p;                 p += WSA((size_t)N * 4);
    int*   blocksum= (int*)p;                   p += WSA((size_t)nsb * 4);
    int*   blockoff= (int*)p;                   p += WSA((size_t)nsb * 4);
    float* den_part= (float*)p;                 p += WSA((size_t)NB_SLG * 4);
    float* num_part= (float*)p;                 p += WSA((size_t)NB_NUM * 4);
    float* ss_part = (float*)p;                 p += WSA((size_t)NB_SST * 256 * 4);
    unsigned long long* csr = (unsigned long long*)p; p += WSA((size_t)E * 8);
    float* ident   = (float*)p;                 p += WSA((size_t)N * 64 * 4);
    float* bufA    = (float*)p;                 p += WSA((size_t)N * 64 * 4);
    float* bufB    = (float*)p;                 p += WSA((size_t)N * 64 * 4);
    float* sbuf    = (float*)p;                 p += WSA((size_t)N * 16 * 4);

    int h0blk    = (N + 3) / 4;
    int aggblk   = (N + 15) / 16;
    int gemmblk  = (N + 15) / 16;

    zero_kernel<<<(N + 255) / 256, 256, 0, stream>>>(deg, N);
    deg_kernel<<<2048, 256, 0, stream>>>(dst, E, deg);
    // hierarchical scan
    partial_kernel<<<nsb, 256, 0, stream>>>(deg, N, blocksum);
    scanblocks_kernel<<<1, 1024, 0, stream>>>(blocksum, nsb, blockoff);
    fillrow_kernel<<<nsb, 256, 0, stream>>>(deg, blockoff, N, E, rowstart, cursor, dis, dis2);
    fill_kernel<<<2048, 256, 0, stream>>>(src, dst, E, cursor, dis, csr);

    // layer 0 (h0 = identity)
    h0_kernel<<<h0blk, 256, 0, stream>>>(x, W0, b0, ident, N);

    // layer 1: T = ident @ W1 -> bufA ; agg -> bufB (relu)
    gemm64_kernel<<<gemmblk, 256, 0, stream>>>(ident, W1, bufA, N);
    agg_kernel<<<aggblk, 256, 0, stream>>>(bufA, csr, rowstart, dis2, b1, ident, bufB, N, AGG_RELU);

    // layer 2: T = bufB @ W2 -> bufA ; agg -> bufB (relu)
    gemm64_kernel<<<gemmblk, 256, 0, stream>>>(bufB, W2, bufA, N);
    agg_kernel<<<aggblk, 256, 0, stream>>>(bufA, csr, rowstart, dis2, b2, ident, bufB, N, AGG_RELU);

    // layer 3: T = bufB @ W3 -> bufA ; agg + identity -> bufB (relu)
    gemm64_kernel<<<gemmblk, 256, 0, stream>>>(bufB, W3, bufA, N);
    agg_kernel<<<aggblk, 256, 0, stream>>>(bufA, csr, rowstart, dis2, b3, ident, bufB, N, AGG_RELU | AGG_IDENT);

    // losses (atomic-free: per-block partials + final reduce)
    slogits_kernel<<<NB_SLG, 256, 0, stream>>>(bufB, Wl, bl, deg, sbuf, den_part, N);
    sst_kernel<<<NB_SST, 256, 0, stream>>>(sbuf, N, ss_part);
    num_kernel<<<NB_NUM, 256, 0, stream>>>(src, dst, sbuf, E, num_part);
    final_kernel<<<1, 256, 0, stream>>>(num_part, den_part, ss_part, outp);
}